// Round 6
// baseline (163.628 us; speedup 1.0000x reference)
//
#include <hip/hip_runtime.h>
#include <math.h>
#include <float.h>

typedef __attribute__((ext_vector_type(8))) short short8;
typedef __attribute__((ext_vector_type(8))) ushort ushort8;
typedef __attribute__((ext_vector_type(4))) float f32x4;

namespace {

constexpr int B = 256;
constexpr int M = 65536;
constexpr int D = 1024;
constexpr float DECAY_EPS = 1e-8f;
constexpr float DECAY_RATE = 0.999f;

constexpr int BN = 32;          // keys per GEMM block
constexpr int BK = 32;          // k per step
constexpr int KSTEPS = D / BK;  // 32

constexpr int CHUNKS = 8;           // top-k chunks per row
constexpr int CHUNK = M / CHUNKS;   // 8192
constexpr int NCAND = CHUNKS * 8;   // 64 candidates per row

__device__ inline ushort f2bf(float f) {
  union { float f; unsigned u; } v; v.f = f;
  unsigned r = v.u + 0x7fffu + ((v.u >> 16) & 1u);  // RNE
  return (ushort)(r >> 16);
}

// ---------------------------------------------------------------------------
// Kernel 1: normalize queries, emit bf16 in MFMA A-fragment order:
// qnf[(kt*16 + mt)*512 + l*8 + j] = qn[mt*16 + (l&15)][kt*32 + (l>>4)*8 + j]
// ---------------------------------------------------------------------------
__global__ void prep_q_kernel(const float* __restrict__ q, ushort* __restrict__ qnf) {
  const int r = blockIdx.x;
  const int t = threadIdx.x;  // 256 threads x float4
  float4 v = reinterpret_cast<const float4*>(q + (size_t)r * D)[t];
  float ss = v.x * v.x + v.y * v.y + v.z * v.z + v.w * v.w;
#pragma unroll
  for (int off = 32; off; off >>= 1) ss += __shfl_down(ss, off, 64);
  __shared__ float red[4];
  if ((t & 63) == 0) red[t >> 6] = ss;
  __syncthreads();
  const float inv = 1.0f / fmaxf(sqrtf(red[0] + red[1] + red[2] + red[3]), DECAY_EPS);
  ushort4 o;
  o.x = f2bf(v.x * inv); o.y = f2bf(v.y * inv);
  o.z = f2bf(v.z * inv); o.w = f2bf(v.w * inv);
  const int k0 = t * 4;
  const int kt = k0 >> 5;
  const int lane_slot = (r & 15) + 16 * ((k0 & 31) >> 3);
  const int j0 = k0 & 7;  // 0 or 4
  *reinterpret_cast<ushort4*>(qnf + (size_t)(kt * 16 + (r >> 4)) * 512 + lane_slot * 8 + j0) = o;
}

// ---------------------------------------------------------------------------
// Kernel 2: bf16-MFMA scores -> bf16 score matrix [B][M].
// BM=256 (all rows) x BN=32 keys per block, BK=32, 512 thr (8 waves).
// Wave w owns m-frags {2w, 2w+1}; acc[2][2]; grid 2048 -> 8 blocks/CU,
// 32 waves/CU resident. Keys reg-staged -> bf16 LDS (r2's conflict-free
// swizzle), loads issued one full step early; nothing in flight at barrier.
// ---------------------------------------------------------------------------
__global__ __launch_bounds__(512, 8) void score_gemm_kernel(
    const ushort* __restrict__ qnf, const float* __restrict__ keys,
    const float* __restrict__ importance, const int* __restrict__ atimes,
    const int* __restrict__ acnts, const int* __restrict__ ctime,
    ushort* __restrict__ scores) {
  __shared__ alignas(16) ushort Bs[2][BN * BK];  // 2 x 2 KB
  __shared__ float cscale[BN];

  const int t = threadIdx.x;
  const int lane = t & 63;
  const int w = t >> 6;      // wave 0..7
  const int h = lane >> 4;   // 0..3
  const int q = lane & 15;   // 0..15
  const int jb = blockIdx.x * BN;

  // staging: thread t -> row rw (0..31), float2 chunk cw (0..15)
  const int rw = t >> 4;
  const int cw = t & 15;
  const float2* kp2 = reinterpret_cast<const float2*>(keys + (size_t)(jb + rw) * D) + cw;
  // LDS write offset (ushort elems): 16B slot (cw>>2) XOR-swizzled by row pair
  const int wo = rw * BK + (((cw >> 2) ^ ((rw >> 1) & 3)) * 4 + (cw & 3)) * 2;

  // frag read offsets (elems): row = nf*16+q, phys 16B slot = h ^ ((row>>1)&3)
  int roff[2];
#pragma unroll
  for (int nf = 0; nf < 2; ++nf) {
    const int row = nf * 16 + q;
    roff[nf] = row * BK + ((h ^ ((row >> 1) & 3)) * 8);
  }

  f32x4 acc[2][2];
#pragma unroll
  for (int f = 0; f < 2; ++f)
#pragma unroll
    for (int n = 0; n < 2; ++n) acc[f][n] = (f32x4)(0.0f);

  float kn2 = 0.0f;
  float2 nv;

  // prologue: stage step 0, issue load for step 1
  nv = kp2[0];
  kn2 += nv.x * nv.x + nv.y * nv.y;
  *reinterpret_cast<uint*>(&Bs[0][wo]) = (uint)f2bf(nv.x) | ((uint)f2bf(nv.y) << 16);
  nv = kp2[16];
  __syncthreads();

  const short8* apbase = reinterpret_cast<const short8*>(qnf);

  for (int s = 0; s < KSTEPS; ++s) {
    const int cur = s & 1;
    // A fragments (L2-resident qnf, coalesced 16B/lane)
    short8 a0 = apbase[(size_t)(s * 16 + 2 * w + 0) * 64 + lane];
    short8 a1 = apbase[(size_t)(s * 16 + 2 * w + 1) * 64 + lane];
    // B fragments from LDS
    short8 b0 = *reinterpret_cast<const short8*>(&Bs[cur][roff[0]]);
    short8 b1 = *reinterpret_cast<const short8*>(&Bs[cur][roff[1]]);
    acc[0][0] = __builtin_amdgcn_mfma_f32_16x16x32_bf16(a0, b0, acc[0][0], 0, 0, 0);
    acc[0][1] = __builtin_amdgcn_mfma_f32_16x16x32_bf16(a0, b1, acc[0][1], 0, 0, 0);
    acc[1][0] = __builtin_amdgcn_mfma_f32_16x16x32_bf16(a1, b0, acc[1][0], 0, 0, 0);
    acc[1][1] = __builtin_amdgcn_mfma_f32_16x16x32_bf16(a1, b1, acc[1][1], 0, 0, 0);
    if (s + 1 < KSTEPS) {
      kn2 += nv.x * nv.x + nv.y * nv.y;
      *reinterpret_cast<uint*>(&Bs[cur ^ 1][wo]) =
          (uint)f2bf(nv.x) | ((uint)f2bf(nv.y) << 16);
      if (s + 2 < KSTEPS) nv = kp2[(s + 2) * 16];
    }
    __syncthreads();
  }

  // key norms: 16 staging threads per row are consecutive lanes (q = chunk)
  kn2 += __shfl_xor(kn2, 1, 64);
  kn2 += __shfl_xor(kn2, 2, 64);
  kn2 += __shfl_xor(kn2, 4, 64);
  kn2 += __shfl_xor(kn2, 8, 64);
  if (q == 0) {
    const int j = jb + rw;  // rw == w*4 + h
    const float dt = (float)(ctime[0] - atimes[j]);
    const float mult = powf(DECAY_RATE, dt) * importance[j] * log1pf((float)acnts[j]);
    cscale[rw] = mult / fmaxf(sqrtf(kn2), DECAY_EPS);
  }
  __syncthreads();

  // epilogue: C/D col = q, row = h*4 + rr; pack col pairs via shfl, u32 store
#pragma unroll
  for (int f = 0; f < 2; ++f) {
    const int row0 = (2 * w + f) * 16 + (h << 2);
#pragma unroll
    for (int nf = 0; nf < 2; ++nf) {
      const float cs = cscale[nf * 16 + q];
#pragma unroll
      for (int rr = 0; rr < 4; ++rr) {
        const float v = acc[f][nf][rr] * cs;
        const float vn = __shfl_xor(v, 1, 64);
        if (!(q & 1)) {
          const uint pk = (uint)f2bf(v) | ((uint)f2bf(vn) << 16);
          *reinterpret_cast<uint*>(
              scores + (size_t)(row0 + rr) * M + jb + nf * 16 + q) = pk;
        }
      }
    }
  }
}

// ---------------------------------------------------------------------------
// Kernel 3 (stage A): per (row, chunk) top-8 indices over bf16 scores.
// Packed u32 = (monotone_key16 << 16) | global_idx16; integer compares.
// ---------------------------------------------------------------------------
__global__ __launch_bounds__(256) void topk_partial_kernel(
    const ushort* __restrict__ scores, int* __restrict__ cand_i) {
  const int b = blockIdx.y;
  const int c = blockIdx.x;
  const int t = threadIdx.x;
  const int lane = t & 63, w = t >> 6;
  const ushort8* base8 =
      reinterpret_cast<const ushort8*>(scores + (size_t)b * M + (size_t)c * CHUNK);

  uint s8[8];
#pragma unroll
  for (int i = 0; i < 8; ++i) s8[i] = 0;

  auto ins = [&](uint x) {
    if (x > s8[0]) {
#pragma unroll
      for (int i = 0; i < 8; ++i) {
        const bool up = (i < 7) && (x > s8[i + 1]);
        const uint keep = (x > s8[i]) ? x : s8[i];
        s8[i] = up ? s8[i + 1] : keep;
      }
    }
  };

  const uint jbase = (uint)c * CHUNK;
#pragma unroll
  for (int it = 0; it < CHUNK / (256 * 8); ++it) {  // 4 iters
    const int slot = it * 256 + t;
    const ushort8 v = base8[slot];
    const uint j0 = jbase + (uint)slot * 8;
#pragma unroll
    for (int e = 0; e < 8; ++e) {
      const ushort s = (ushort)v[e];
      const ushort key = (s & 0x8000) ? (ushort)~s : (ushort)(s | 0x8000);
      ins(((uint)key << 16) | ((j0 + e) & 0xFFFFu));
    }
  }

  __shared__ uint ls[2048];
#pragma unroll
  for (int i = 0; i < 8; ++i) ls[t * 8 + i] = s8[i];
  __syncthreads();

  __shared__ uint rs4[4];
  __shared__ int rp4[4];
  for (int r = 0; r < 8; ++r) {
    uint ms = 0;
    int mp = 0;
#pragma unroll
    for (int i = 0; i < 8; ++i) {
      const uint v = ls[i * 256 + t];
      if (v > ms) { ms = v; mp = i * 256 + t; }
    }
#pragma unroll
    for (int off = 32; off; off >>= 1) {
      const uint ov = __shfl_xor(ms, off, 64);
      const int op = __shfl_xor(mp, off, 64);
      if (ov > ms) { ms = ov; mp = op; }
    }
    if (lane == 0) { rs4[w] = ms; rp4[w] = mp; }
    __syncthreads();
    if (t == 0) {
      uint bs = 0;
      int bp = 0;
#pragma unroll
      for (int i = 0; i < 4; ++i)
        if (rs4[i] > bs) { bs = rs4[i]; bp = rp4[i]; }
      cand_i[((size_t)b * CHUNKS + c) * 8 + r] = (int)(ls[bp] & 0xFFFFu);
      ls[bp] = 0;
    }
    __syncthreads();
  }
}

// ---------------------------------------------------------------------------
// Kernel 4 (stage B): exact fp32 rescore of 64 candidates, top-8, softmax,
// weighted value gather. One block (512 thr = 8 waves) per row.
// ---------------------------------------------------------------------------
__global__ __launch_bounds__(512) void rescore_kernel(
    const int* __restrict__ cand_i, const float* __restrict__ query,
    const float* __restrict__ keys, const float* __restrict__ values,
    const float* __restrict__ importance, const int* __restrict__ atimes,
    const int* __restrict__ acnts, const int* __restrict__ ctime,
    float* __restrict__ outc, float* __restrict__ conf) {
  const int b = blockIdx.x;
  const int t = threadIdx.x;
  const int lane = t & 63, w = t >> 6;

  const float4* qv4 = reinterpret_cast<const float4*>(query + (size_t)b * D + lane * 16);
  float4 q0 = qv4[0], q1 = qv4[1], q2 = qv4[2], q3 = qv4[3];
  float ssq = q0.x * q0.x + q0.y * q0.y + q0.z * q0.z + q0.w * q0.w
            + q1.x * q1.x + q1.y * q1.y + q1.z * q1.z + q1.w * q1.w
            + q2.x * q2.x + q2.y * q2.y + q2.z * q2.z + q2.w * q2.w
            + q3.x * q3.x + q3.y * q3.y + q3.z * q3.z + q3.w * q3.w;
#pragma unroll
  for (int off = 32; off; off >>= 1) ssq += __shfl_xor(ssq, off, 64);
  const float qdn = fmaxf(sqrtf(ssq), DECAY_EPS);
  const int ct = ctime[0];

  __shared__ float sc[NCAND];
  __shared__ int sidx[NCAND];

  for (int u = 0; u < 8; ++u) {
    const int c = w * 8 + u;
    const int j = cand_i[(size_t)b * NCAND + c];
    const float4* kv4 = reinterpret_cast<const float4*>(keys + (size_t)j * D + lane * 16);
    const float4 k0 = kv4[0], k1 = kv4[1], k2 = kv4[2], k3 = kv4[3];
    float dd = q0.x * k0.x + q0.y * k0.y + q0.z * k0.z + q0.w * k0.w
             + q1.x * k1.x + q1.y * k1.y + q1.z * k1.z + q1.w * k1.w
             + q2.x * k2.x + q2.y * k2.y + q2.z * k2.z + q2.w * k2.w
             + q3.x * k3.x + q3.y * k3.y + q3.z * k3.z + q3.w * k3.w;
    float nn = k0.x * k0.x + k0.y * k0.y + k0.z * k0.z + k0.w * k0.w
             + k1.x * k1.x + k1.y * k1.y + k1.z * k1.z + k1.w * k1.w
             + k2.x * k2.x + k2.y * k2.y + k2.z * k2.z + k2.w * k2.w
             + k3.x * k3.x + k3.y * k3.y + k3.z * k3.z + k3.w * k3.w;
#pragma unroll
    for (int off = 32; off; off >>= 1) {
      dd += __shfl_xor(dd, off, 64);
      nn += __shfl_xor(nn, off, 64);
    }
    if (lane == 0) {
      const float dtv = (float)(ct - atimes[j]);
      const float mult = powf(DECAY_RATE, dtv) * importance[j] * log1pf((float)acnts[j]);
      sc[c] = dd / (qdn * fmaxf(sqrtf(nn), DECAY_EPS)) * mult;
      sidx[c] = j;
    }
  }
  __syncthreads();

  __shared__ float w8s[8];
  __shared__ int g8[8];
  __shared__ float confv;
  __shared__ float tls[8];
  __shared__ int tli[8];
  if (w == 0) {
    float myv = sc[lane];
    for (int r = 0; r < 8; ++r) {
      float m = myv;
      int mi = lane;
#pragma unroll
      for (int off = 32; off; off >>= 1) {
        const float ov = __shfl_xor(m, off, 64);
        const int oi = __shfl_xor(mi, off, 64);
        if (ov > m || (ov == m && oi < mi)) { m = ov; mi = oi; }
      }
      if (lane == 0) { tls[r] = m; tli[r] = mi; }
      if (lane == mi) myv = -FLT_MAX;
    }
    if (lane == 0) {
      const float mx = tls[0];
      float e[8];
      float z = 0.0f;
#pragma unroll
      for (int r = 0; r < 8; ++r) { e[r] = expf(tls[r] - mx); z += e[r]; }
      const float invz = 1.0f / z;
#pragma unroll
      for (int r = 0; r < 8; ++r) { w8s[r] = e[r] * invz; g8[r] = sidx[tli[r]]; }
      confv = w8s[0];
    }
  }
  __syncthreads();

  float2 acc = make_float2(0.0f, 0.0f);
#pragma unroll
  for (int k = 0; k < 8; ++k) {
    const float wk = w8s[k];
    const float2 v = *reinterpret_cast<const float2*>(values + (size_t)g8[k] * D + 2 * t);
    acc.x = fmaf(wk, v.x, acc.x);
    acc.y = fmaf(wk, v.y, acc.y);
  }
  *reinterpret_cast<float2*>(outc + (size_t)b * D + 2 * t) = acc;
  if (t == 0) conf[b] = confv;
}

}  // namespace

extern "C" void kernel_launch(void* const* d_in, const int* in_sizes, int n_in,
                              void* d_out, int out_size, void* d_ws, size_t ws_size,
                              hipStream_t stream) {
  const float* query = (const float*)d_in[0];
  const float* keys = (const float*)d_in[1];
  const float* values = (const float*)d_in[2];
  const float* importance = (const float*)d_in[3];
  const int* atimes = (const int*)d_in[4];
  const int* acnts = (const int*)d_in[5];
  const int* ctime = (const int*)d_in[6];

  float* out = (float*)d_out;  // combined [B*D] then confidence [B]
  ushort* qnf = (ushort*)d_ws;                                   // 512 KB
  ushort* scores = qnf + (size_t)B * D;                          // 32 MB bf16
  int* cand = (int*)(scores + (size_t)B * M);                    // 64 KB

  prep_q_kernel<<<B, 256, 0, stream>>>(query, qnf);
  score_gemm_kernel<<<M / BN, 512, 0, stream>>>(qnf, keys, importance, atimes,
                                                acnts, ctime, scores);
  dim3 gA(CHUNKS, B);
  topk_partial_kernel<<<gA, 256, 0, stream>>>(scores, cand);
  rescore_kernel<<<B, 512, 0, stream>>>(cand, query, keys, values, importance,
                                        atimes, acnts, ctime, out, out + (size_t)B * D);
}